// Round 10
// baseline (492.842 us; speedup 1.0000x reference)
//
#include <hip/hip_runtime.h>
#include <hip/hip_bf16.h>

#define NN 50000
#define NE 500000
#define HID 128
#define LAYERS 3
#define RELS 8
#define BASES 30
#define GRAPHS 16
#define CLASSES 8
#define EPSV 1e-5f
#define NOUT (HID * (RELS + 1))   // 1152
#define SCAN_CHUNK 1024
#define SCAN_NBLK ((NN + SCAN_CHUNK - 1) / SCAN_CHUNK)   // 49
#define PCHUNK 128

typedef __attribute__((ext_vector_type(8))) short short8;   // 8 bf16 (4 VGPRs)
typedef __attribute__((ext_vector_type(4))) float f32x4;    // MFMA accumulator
typedef __attribute__((ext_vector_type(2))) float f32x2;

__device__ __forceinline__ float bf2f(unsigned short u) {
    union { unsigned int i; float f; } x; x.i = ((unsigned int)u) << 16; return x.f;
}
__device__ __forceinline__ unsigned short f2bf(float f) {
    __hip_bfloat16 b = __float2bfloat16(f);
    return *(unsigned short*)&b;
}
// HW fp8 (OCP e4m3 on gfx950) pack/unpack
__device__ __forceinline__ f32x2 fp8x2_2f(unsigned short u) {
    return __builtin_amdgcn_cvt_pk_f32_fp8((int)u, false);
}

// ---------------- wT: [L][1152 n][128 k] bf16
// block = (l, k-pair); lanes span j (coalesced basis reads); all 8 relations per load.
__global__ __launch_bounds__(256) void build_wcat(const float* __restrict__ basis,
                                                  const float* __restrict__ comp,
                                                  const float* __restrict__ root,
                                                  unsigned short* __restrict__ wT) {
    int bid = blockIdx.x;
    int l = bid >> 6;               // 0..2
    int k0 = (bid & 63) << 1;       // 0,2,..,126
    __shared__ float cl[RELS * BASES];   // 240
    int tid = threadIdx.x;
    if (tid < RELS * BASES) cl[tid] = comp[l * RELS * BASES + tid];
    __syncthreads();
    int j = tid & 127;
    int k = k0 + (tid >> 7);
    const float* bp = basis + ((size_t)l * BASES * HID + k) * HID + j;
    float acc[RELS];
#pragma unroll
    for (int r = 0; r < RELS; ++r) acc[r] = 0.f;
    for (int b = 0; b < BASES; ++b) {
        float v = bp[(size_t)b * HID * HID];
#pragma unroll
        for (int r = 0; r < RELS; ++r) acc[r] += cl[r * BASES + b] * v;
    }
    unsigned short* wl = wT + (size_t)l * NOUT * HID;
#pragma unroll
    for (int r = 0; r < RELS; ++r)
        wl[(size_t)((1 + r) * HID + j) * HID + k] = f2bf(acc[r]);
    // root columns: wT[l][j][k] = root[l][k][j]
    wl[(size_t)j * HID + k] = f2bf(root[((size_t)l * HID + k) * HID + j]);
}

// ---------------- BN1 (eval mode) -> bf16
__global__ void bn1_kernel(const float* __restrict__ x, const float* __restrict__ gamma,
                           const float* __restrict__ beta, const float* __restrict__ mean,
                           const float* __restrict__ var, unsigned short* __restrict__ habf) {
    int idx = blockIdx.x * blockDim.x + threadIdx.x;
    if (idx >= NN * HID) return;
    int f = idx & (HID - 1);
    habf[idx] = f2bf((x[idx] - mean[f]) * rsqrtf(var[f] + EPSV) * gamma[f] + beta[f]);
}

// ---------------- degree count per (dst, rel)
__global__ void deg_kernel(const int* __restrict__ ei, const int* __restrict__ ea,
                           float* __restrict__ deg) {
    int e = blockIdx.x * blockDim.x + threadIdx.x;
    if (e >= NE) return;
    int dst = ei[NE + e];
    atomicAdd(&deg[(size_t)dst * RELS + ea[e]], 1.0f);
}

// degi = int total degree; deg -> invdeg in-place
__global__ void invdeg_kernel(float* __restrict__ deg, int* __restrict__ degi) {
    int n = blockIdx.x * blockDim.x + threadIdx.x;
    if (n >= NN) return;
    float s = 0.f;
#pragma unroll
    for (int r = 0; r < RELS; ++r) {
        float d = deg[(size_t)n * RELS + r];
        s += d;
        deg[(size_t)n * RELS + r] = 1.0f / fmaxf(d, 1.0f);
    }
    degi[n] = (int)(s + 0.5f);
}

// ---------------- exclusive scan of degi -> rowptr
__global__ __launch_bounds__(256) void scan_partial(const int* __restrict__ degi,
                                                    int* __restrict__ rowptr,
                                                    int* __restrict__ bsum) {
    __shared__ int ssc[256];
    int t = threadIdx.x;
    int base = blockIdx.x * SCAN_CHUNK + t * 4;
    int v[4];
#pragma unroll
    for (int j = 0; j < 4; ++j) v[j] = (base + j < NN) ? degi[base + j] : 0;
    int tsum = v[0] + v[1] + v[2] + v[3];
    ssc[t] = tsum;
    __syncthreads();
    for (int ofs = 1; ofs < 256; ofs <<= 1) {
        int add = (t >= ofs) ? ssc[t - ofs] : 0;
        __syncthreads();
        ssc[t] += add;
        __syncthreads();
    }
    int excl = ssc[t] - tsum;
    int e = 0;
#pragma unroll
    for (int j = 0; j < 4; ++j) {
        if (base + j < NN) rowptr[base + j] = excl + e;
        e += v[j];
    }
    if (t == 255) bsum[blockIdx.x] = ssc[255];
}

__global__ void scan_bsum(int* __restrict__ bsum) {
    if (threadIdx.x == 0) {
        int acc = 0;
        for (int b = 0; b < SCAN_NBLK; ++b) { int v = bsum[b]; bsum[b] = acc; acc += v; }
    }
}

__global__ __launch_bounds__(256) void scan_add(int* __restrict__ rowptr,
                                                const int* __restrict__ bsum) {
    int i = blockIdx.x * blockDim.x + threadIdx.x;
    if (i < NN) rowptr[i] += bsum[i >> 10];
    if (i == 0) rowptr[NN] = NE;
}

// ---------------- fill CSR
__global__ void fill_kernel(const int* __restrict__ ei, const int* __restrict__ ea,
                            const int* __restrict__ rowptr, const float* __restrict__ invdeg,
                            int* __restrict__ fillcnt, int* __restrict__ epk,
                            float* __restrict__ escale) {
    int e = blockIdx.x * blockDim.x + threadIdx.x;
    if (e >= NE) return;
    int src = ei[e];
    int dst = ei[NE + e];
    int r = ea[e];
    int pos = atomicAdd(&fillcnt[dst], 1);
    int slot = rowptr[dst] + pos;
    epk[slot] = src | (r << 20);
    escale[slot] = invdeg[(size_t)dst * RELS + r];
}

// ---------------- MFMA GEMM (transposed D = W·A^T), XOR-swizzled LDS.
// One block = 64-src stripe, loops all 9 feature tiles. Thread holds 4 consecutive
// feats per src row -> packed u32 fp8 / uint2 bf16 stores.
__global__ __launch_bounds__(256) void gemm_mfma(const unsigned short* __restrict__ habf,
                                                 const unsigned short* __restrict__ wT,
                                                 const float* __restrict__ bias,
                                                 unsigned short* __restrict__ hnb,
                                                 unsigned char* __restrict__ xwb) {
    __shared__ __align__(16) unsigned short As[64][128];   // src x k, 16B-unit XOR swizzle
    __shared__ __align__(16) unsigned short Bs[128][64];   // feat x k-half, swizzled
    int tid = threadIdx.x;
    int wave = tid >> 6, lane = tid & 63;
    int wm = (wave & 1) * 32;      // src sub-stripe
    int wn = (wave >> 1) * 64;     // feat sub-stripe
    int quad = lane >> 4, l16 = lane & 15;
    int row0 = blockIdx.x * 64;

    // stage A once: 4 threads/row, 4 x 16B units each, swizzled
    {
        int r = tid >> 2;
        int u0 = (tid & 3) * 4;
        int grow = row0 + r;
        const uint4* ga = (const uint4*)(habf + (size_t)grow * HID + u0 * 8);
        uint4 z = {0u, 0u, 0u, 0u};
#pragma unroll
        for (int q = 0; q < 4; ++q) {
            int pu = (u0 + q) ^ (r & 7);
            *(uint4*)&As[r][pu << 3] = (grow < NN) ? ga[q] : z;
        }
    }

    for (int n0 = 0; n0 < RELS + 1; ++n0) {
        f32x4 acc[2][4];
#pragma unroll
        for (int i = 0; i < 2; ++i)
#pragma unroll
            for (int j = 0; j < 4; ++j) acc[i][j] = (f32x4){0.f, 0.f, 0.f, 0.f};

#pragma unroll
        for (int kh = 0; kh < 2; ++kh) {
            __syncthreads();   // previous MFMA reads of Bs done (or A staged, first pass)
            {
                int r = tid >> 1;
                int u0 = (tid & 1) * 4;
                const uint4* gb = (const uint4*)(wT + (size_t)(n0 * 128 + r) * HID + kh * 64 + u0 * 8);
#pragma unroll
                for (int q = 0; q < 4; ++q) {
                    int pu = (u0 + q) ^ (r & 7);
                    *(uint4*)&Bs[r][pu << 3] = gb[q];
                }
            }
            __syncthreads();
#pragma unroll
            for (int kc = 0; kc < 2; ++kc) {
                short8 aop[4], bop[2];
#pragma unroll
                for (int j = 0; j < 4; ++j) {   // A-operand: weight rows (feat = lane&15)
                    int fr = wn + j * 16 + l16;
                    int pu = (kc * 4 + quad) ^ (l16 & 7);
                    aop[j] = *(const short8*)&Bs[fr][pu << 3];
                }
#pragma unroll
                for (int i = 0; i < 2; ++i) {   // B-operand: activation rows (src = lane&15)
                    int sr = wm + i * 16 + l16;
                    int pu = (kh * 8 + kc * 4 + quad) ^ (l16 & 7);
                    bop[i] = *(const short8*)&As[sr][pu << 3];
                }
#pragma unroll
                for (int i = 0; i < 2; ++i)
#pragma unroll
                    for (int j = 0; j < 4; ++j)
                        acc[i][j] = __builtin_amdgcn_mfma_f32_16x16x32_bf16(aop[j], bop[i], acc[i][j], 0, 0, 0);
            }
        }

        // epilogue: D[feat][src] -> thread owns src = wm+i*16+l16, feats f0..f0+3
        if (n0 == 0) {
#pragma unroll
            for (int i = 0; i < 2; ++i) {
                int src = row0 + wm + i * 16 + l16;
                if (src >= NN) continue;
#pragma unroll
                for (int j = 0; j < 4; ++j) {
                    int f0 = wn + j * 16 + quad * 4;
                    unsigned lo = (unsigned)f2bf(acc[i][j][0] + bias[f0 + 0]) |
                                  ((unsigned)f2bf(acc[i][j][1] + bias[f0 + 1]) << 16);
                    unsigned hi = (unsigned)f2bf(acc[i][j][2] + bias[f0 + 2]) |
                                  ((unsigned)f2bf(acc[i][j][3] + bias[f0 + 3]) << 16);
                    uint2 pk = {lo, hi};
                    *(uint2*)(hnb + (size_t)src * HID + f0) = pk;
                }
            }
        } else {
            int cbase = (n0 - 1) * 128;
#pragma unroll
            for (int i = 0; i < 2; ++i) {
                int src = row0 + wm + i * 16 + l16;
                if (src >= NN) continue;
#pragma unroll
                for (int j = 0; j < 4; ++j) {
                    int f0 = wn + j * 16 + quad * 4;
                    unsigned w = (unsigned)__builtin_amdgcn_cvt_pk_fp8_f32(acc[i][j][0], acc[i][j][1], 0, false);
                    w = (unsigned)__builtin_amdgcn_cvt_pk_fp8_f32(acc[i][j][2], acc[i][j][3], (int)w, true);
                    *(unsigned*)(xwb + (size_t)src * (RELS * HID) + cbase + f0) = w;
                }
            }
        }
    }
}

// ---------------- aggregate (atomic-free): one wave per dst node, edge prefetch + shfl
// habf[dst] = bf16(relu(hnb[dst] + sum_edges fp8(xwb[src][r]) * escale))
__global__ __launch_bounds__(256) void aggregate_kernel(const int* __restrict__ rowptr,
                                                        const int* __restrict__ epk,
                                                        const float* __restrict__ escale,
                                                        const unsigned char* __restrict__ xwb,
                                                        const unsigned short* __restrict__ hnb,
                                                        unsigned short* __restrict__ habf) {
    int node = (blockIdx.x << 2) + (threadIdx.x >> 6);
    if (node >= NN) return;
    int lane = threadIdx.x & 63;
    int beg = rowptr[node], end = rowptr[node + 1];
    float ax = 0.f, ay = 0.f;
    for (int b0 = beg; b0 < end; b0 += 64) {
        int cnt = min(64, end - b0);
        int myp = 0; float mys = 0.f;
        if (lane < cnt) { myp = epk[b0 + lane]; mys = escale[b0 + lane]; }
        int j = 0;
        for (; j + 4 <= cnt; j += 4) {
            int p0 = __shfl(myp, j),     p1 = __shfl(myp, j + 1);
            int p2 = __shfl(myp, j + 2), p3 = __shfl(myp, j + 3);
            float s0 = __shfl(mys, j),     s1 = __shfl(mys, j + 1);
            float s2 = __shfl(mys, j + 2), s3 = __shfl(mys, j + 3);
            unsigned short u0 = *(const unsigned short*)(xwb + (size_t)(p0 & 0xFFFFF) * (RELS * HID) + (p0 >> 20) * HID + lane * 2);
            unsigned short u1 = *(const unsigned short*)(xwb + (size_t)(p1 & 0xFFFFF) * (RELS * HID) + (p1 >> 20) * HID + lane * 2);
            unsigned short u2 = *(const unsigned short*)(xwb + (size_t)(p2 & 0xFFFFF) * (RELS * HID) + (p2 >> 20) * HID + lane * 2);
            unsigned short u3 = *(const unsigned short*)(xwb + (size_t)(p3 & 0xFFFFF) * (RELS * HID) + (p3 >> 20) * HID + lane * 2);
            f32x2 v0 = fp8x2_2f(u0), v1 = fp8x2_2f(u1), v2 = fp8x2_2f(u2), v3 = fp8x2_2f(u3);
            ax += v0.x * s0 + v1.x * s1 + v2.x * s2 + v3.x * s3;
            ay += v0.y * s0 + v1.y * s1 + v2.y * s2 + v3.y * s3;
        }
        for (; j < cnt; ++j) {
            int p = __shfl(myp, j);
            float s = __shfl(mys, j);
            unsigned short u = *(const unsigned short*)(xwb + (size_t)(p & 0xFFFFF) * (RELS * HID) + (p >> 20) * HID + lane * 2);
            f32x2 v = fp8x2_2f(u);
            ax += v.x * s;
            ay += v.y * s;
        }
    }
    ushort2 cu = *((const ushort2*)(hnb + (size_t)node * HID) + lane);
    ushort2 o;
    o.x = f2bf(fmaxf(bf2f(cu.x) + ax, 0.f));
    o.y = f2bf(fmaxf(bf2f(cu.y) + ay, 0.f));
    *((ushort2*)(habf + (size_t)node * HID) + lane) = o;
}

// ---------------- global mean pool: sorted-batch register accumulation, flush on g-change
__global__ __launch_bounds__(256) void pool_kernel(const unsigned short* __restrict__ habf,
                                                   const int* __restrict__ batch,
                                                   float* __restrict__ psum,
                                                   float* __restrict__ pcnt) {
    int tid = threadIdx.x;
    int f = tid & 127;
    int sub = tid >> 7;
    int base = blockIdx.x * PCHUNK;
    float acc = 0.f, cnt = 0.f;
    int gcur = -1;
    for (int it = 0; it < PCHUNK / 2; ++it) {
        int node = base + it * 2 + sub;
        if (node >= NN) break;
        int g = batch[node];
        if (g != gcur) {
            if (gcur >= 0) {
                atomicAdd(&psum[gcur * HID + f], acc);
                if (f == 0) atomicAdd(&pcnt[gcur], cnt);
            }
            gcur = g; acc = 0.f; cnt = 0.f;
        }
        acc += bf2f(habf[(size_t)node * HID + f]);
        cnt += 1.f;
    }
    if (gcur >= 0) {
        atomicAdd(&psum[gcur * HID + f], acc);
        if (f == 0) atomicAdd(&pcnt[gcur], cnt);
    }
}

// ---------------- head
__global__ void head_kernel(const float* __restrict__ psum, const float* __restrict__ pcnt,
                            const float* __restrict__ g2, const float* __restrict__ b2,
                            const float* __restrict__ m2, const float* __restrict__ v2,
                            const float* __restrict__ fc1w, const float* __restrict__ fc1b,
                            const float* __restrict__ fc2w, const float* __restrict__ fc2b,
                            float* __restrict__ out) {
    __shared__ float v[HID];
    __shared__ float u[HID];
    __shared__ float lg[CLASSES];
    int j = threadIdx.x;
    float acc = 0.f;
    for (int g = 0; g < GRAPHS; ++g) {
        float val = psum[g * HID + j] / fmaxf(pcnt[g], 1.0f);
        val = (val - m2[j]) * rsqrtf(v2[j] + EPSV) * g2[j] + b2[j];
        acc += val;
    }
    v[j] = fmaxf(acc / (float)GRAPHS, 0.f);
    __syncthreads();
    float s = fc1b[j];
    for (int k = 0; k < HID; ++k) s += v[k] * fc1w[k * HID + j];
    u[j] = fmaxf(s, 0.f);
    __syncthreads();
    if (j < CLASSES) {
        float t = fc2b[j];
        for (int k = 0; k < HID; ++k) t += u[k] * fc2w[k * CLASSES + j];
        lg[j] = t;
    }
    __syncthreads();
    if (j < CLASSES) {
        float mx = lg[0];
        for (int c = 1; c < CLASSES; ++c) mx = fmaxf(mx, lg[c]);
        float se = 0.f;
        for (int c = 0; c < CLASSES; ++c) se += expf(lg[c] - mx);
        out[j] = lg[j] - mx - logf(se);
    }
}

extern "C" void kernel_launch(void* const* d_in, const int* in_sizes, int n_in,
                              void* d_out, int out_size, void* d_ws, size_t ws_size,
                              hipStream_t stream) {
    const float* x     = (const float*)d_in[0];
    const int*   ei    = (const int*)d_in[1];
    const int*   ea    = (const int*)d_in[2];
    const int*   batch = (const int*)d_in[3];
    const float* bn1g  = (const float*)d_in[4];
    const float* bn1b  = (const float*)d_in[5];
    const float* bn1m  = (const float*)d_in[6];
    const float* bn1v  = (const float*)d_in[7];
    const float* basis = (const float*)d_in[8];
    const float* comp  = (const float*)d_in[9];
    const float* root  = (const float*)d_in[10];
    const float* bias  = (const float*)d_in[11];
    const float* bn2g  = (const float*)d_in[12];
    const float* bn2b  = (const float*)d_in[13];
    const float* bn2m  = (const float*)d_in[14];
    const float* bn2v  = (const float*)d_in[15];
    const float* fc1w  = (const float*)d_in[16];
    const float* fc1b  = (const float*)d_in[17];
    const float* fc2w  = (const float*)d_in[18];
    const float* fc2b  = (const float*)d_in[19];

    float* ws = (float*)d_ws;
    size_t off = 0;
    unsigned short* wT = (unsigned short*)(ws + off); off += (size_t)LAYERS * NOUT * HID / 2;
    unsigned short* hnb  = (unsigned short*)(ws + off); off += (size_t)NN * HID / 2;
    unsigned short* habf = (unsigned short*)(ws + off); off += (size_t)NN * HID / 2;
    float* deg    = ws + off; off += (size_t)NN * RELS;
    float* psum   = ws + off; off += (size_t)GRAPHS * HID + GRAPHS;
    float* pcnt   = psum + GRAPHS * HID;
    float* escale = ws + off; off += (size_t)NE;
    int* degi     = (int*)(ws + off); off += (size_t)NN;
    int* rowptr   = (int*)(ws + off); off += (size_t)NN + 1;
    int* fillcnt  = (int*)(ws + off); off += (size_t)NN;
    int* bsum     = (int*)(ws + off); off += (size_t)SCAN_NBLK;
    int* epk      = (int*)(ws + off); off += (size_t)NE;
    off = (off + 3) & ~(size_t)3;
    unsigned char* xwb = (unsigned char*)(ws + off);
    off += (size_t)NN * RELS * HID / 4;                 // fp8: 51.2 MB
    if (ws_size < off * sizeof(float)) return;

    hipMemsetAsync(psum, 0, (GRAPHS * HID + GRAPHS) * sizeof(float), stream);
    hipMemsetAsync(deg, 0, (size_t)NN * RELS * sizeof(float), stream);
    hipMemsetAsync(fillcnt, 0, (size_t)NN * sizeof(int), stream);

    build_wcat<<<LAYERS * 64, 256, 0, stream>>>(basis, comp, root, wT);
    bn1_kernel<<<(NN * HID + 255) / 256, 256, 0, stream>>>(x, bn1g, bn1b, bn1m, bn1v, habf);

    deg_kernel<<<(NE + 255) / 256, 256, 0, stream>>>(ei, ea, deg);
    invdeg_kernel<<<(NN + 255) / 256, 256, 0, stream>>>(deg, degi);
    scan_partial<<<SCAN_NBLK, 256, 0, stream>>>(degi, rowptr, bsum);
    scan_bsum<<<1, 64, 0, stream>>>(bsum);
    scan_add<<<(NN + 255) / 256, 256, 0, stream>>>(rowptr, bsum);
    fill_kernel<<<(NE + 255) / 256, 256, 0, stream>>>(ei, ea, rowptr, deg, fillcnt, epk, escale);

    for (int l = 0; l < LAYERS; ++l) {
        gemm_mfma<<<(NN + 63) / 64, 256, 0, stream>>>(habf, wT + (size_t)l * NOUT * HID,
                                                      bias + (size_t)l * HID, hnb, xwb);
        aggregate_kernel<<<(NN + 3) / 4, 256, 0, stream>>>(rowptr, epk, escale, xwb, hnb, habf);
    }

    pool_kernel<<<(NN + PCHUNK - 1) / PCHUNK, 256, 0, stream>>>(habf, batch, psum, pcnt);
    head_kernel<<<1, 128, 0, stream>>>(psum, pcnt, bn2g, bn2b, bn2m, bn2v,
                                       fc1w, fc1b, fc2w, fc2b, (float*)d_out);
}

// Round 11
// 467.718 us; speedup vs baseline: 1.0537x; 1.0537x over previous
//
#include <hip/hip_runtime.h>
#include <hip/hip_bf16.h>

#define NN 50000
#define NE 500000
#define HID 128
#define LAYERS 3
#define RELS 8
#define BASES 30
#define GRAPHS 16
#define CLASSES 8
#define EPSV 1e-5f
#define NOUT (HID * (RELS + 1))   // 1152
#define SCAN_CHUNK 1024
#define SCAN_NBLK ((NN + SCAN_CHUNK - 1) / SCAN_CHUNK)   // 49
#define PCHUNK 128

typedef __attribute__((ext_vector_type(8))) short short8;   // 8 bf16 (4 VGPRs)
typedef __attribute__((ext_vector_type(4))) float f32x4;    // MFMA accumulator
typedef __attribute__((ext_vector_type(2))) float f32x2;

__device__ __forceinline__ float bf2f(unsigned short u) {
    union { unsigned int i; float f; } x; x.i = ((unsigned int)u) << 16; return x.f;
}
__device__ __forceinline__ unsigned short f2bf(float f) {
    __hip_bfloat16 b = __float2bfloat16(f);
    return *(unsigned short*)&b;
}
// HW fp8 (OCP e4m3 on gfx950) pack/unpack
__device__ __forceinline__ unsigned char f2fp8(float a) {
    return (unsigned char)(__builtin_amdgcn_cvt_pk_fp8_f32(a, a, 0, false) & 0xFF);
}
__device__ __forceinline__ f32x2 fp8x2_2f(unsigned short u) {
    return __builtin_amdgcn_cvt_pk_f32_fp8((int)u, false);
}

// ---------------- wT: [L][1152 n][128 k] bf16
// block = (l, k-pair); lanes span j (coalesced basis reads); all 8 relations per load.
__global__ __launch_bounds__(256) void build_wcat(const float* __restrict__ basis,
                                                  const float* __restrict__ comp,
                                                  const float* __restrict__ root,
                                                  unsigned short* __restrict__ wT) {
    int bid = blockIdx.x;
    int l = bid >> 6;               // 0..2
    int k0 = (bid & 63) << 1;       // 0,2,..,126
    __shared__ float cl[RELS * BASES];   // 240
    int tid = threadIdx.x;
    if (tid < RELS * BASES) cl[tid] = comp[l * RELS * BASES + tid];
    __syncthreads();
    int j = tid & 127;
    int k = k0 + (tid >> 7);
    const float* bp = basis + ((size_t)l * BASES * HID + k) * HID + j;
    float acc[RELS];
#pragma unroll
    for (int r = 0; r < RELS; ++r) acc[r] = 0.f;
    for (int b = 0; b < BASES; ++b) {
        float v = bp[(size_t)b * HID * HID];
#pragma unroll
        for (int r = 0; r < RELS; ++r) acc[r] += cl[r * BASES + b] * v;
    }
    unsigned short* wl = wT + (size_t)l * NOUT * HID;
#pragma unroll
    for (int r = 0; r < RELS; ++r)
        wl[(size_t)((1 + r) * HID + j) * HID + k] = f2bf(acc[r]);
    // root columns: wT[l][j][k] = root[l][k][j]
    wl[(size_t)j * HID + k] = f2bf(root[((size_t)l * HID + k) * HID + j]);
}

// ---------------- BN1 (eval mode) -> bf16
__global__ void bn1_kernel(const float* __restrict__ x, const float* __restrict__ gamma,
                           const float* __restrict__ beta, const float* __restrict__ mean,
                           const float* __restrict__ var, unsigned short* __restrict__ habf) {
    int idx = blockIdx.x * blockDim.x + threadIdx.x;
    if (idx >= NN * HID) return;
    int f = idx & (HID - 1);
    habf[idx] = f2bf((x[idx] - mean[f]) * rsqrtf(var[f] + EPSV) * gamma[f] + beta[f]);
}

// ---------------- degree count per (dst, rel)
__global__ void deg_kernel(const int* __restrict__ ei, const int* __restrict__ ea,
                           float* __restrict__ deg) {
    int e = blockIdx.x * blockDim.x + threadIdx.x;
    if (e >= NE) return;
    int dst = ei[NE + e];
    atomicAdd(&deg[(size_t)dst * RELS + ea[e]], 1.0f);
}

// degi = int total degree; deg -> invdeg in-place
__global__ void invdeg_kernel(float* __restrict__ deg, int* __restrict__ degi) {
    int n = blockIdx.x * blockDim.x + threadIdx.x;
    if (n >= NN) return;
    float s = 0.f;
#pragma unroll
    for (int r = 0; r < RELS; ++r) {
        float d = deg[(size_t)n * RELS + r];
        s += d;
        deg[(size_t)n * RELS + r] = 1.0f / fmaxf(d, 1.0f);
    }
    degi[n] = (int)(s + 0.5f);
}

// ---------------- exclusive scan of degi -> rowptr
__global__ __launch_bounds__(256) void scan_partial(const int* __restrict__ degi,
                                                    int* __restrict__ rowptr,
                                                    int* __restrict__ bsum) {
    __shared__ int ssc[256];
    int t = threadIdx.x;
    int base = blockIdx.x * SCAN_CHUNK + t * 4;
    int v[4];
#pragma unroll
    for (int j = 0; j < 4; ++j) v[j] = (base + j < NN) ? degi[base + j] : 0;
    int tsum = v[0] + v[1] + v[2] + v[3];
    ssc[t] = tsum;
    __syncthreads();
    for (int ofs = 1; ofs < 256; ofs <<= 1) {
        int add = (t >= ofs) ? ssc[t - ofs] : 0;
        __syncthreads();
        ssc[t] += add;
        __syncthreads();
    }
    int excl = ssc[t] - tsum;
    int e = 0;
#pragma unroll
    for (int j = 0; j < 4; ++j) {
        if (base + j < NN) rowptr[base + j] = excl + e;
        e += v[j];
    }
    if (t == 255) bsum[blockIdx.x] = ssc[255];
}

__global__ void scan_bsum(int* __restrict__ bsum) {
    if (threadIdx.x == 0) {
        int acc = 0;
        for (int b = 0; b < SCAN_NBLK; ++b) { int v = bsum[b]; bsum[b] = acc; acc += v; }
    }
}

__global__ __launch_bounds__(256) void scan_add(int* __restrict__ rowptr,
                                                const int* __restrict__ bsum) {
    int i = blockIdx.x * blockDim.x + threadIdx.x;
    if (i < NN) rowptr[i] += bsum[i >> 10];
    if (i == 0) rowptr[NN] = NE;
}

// ---------------- fill CSR
__global__ void fill_kernel(const int* __restrict__ ei, const int* __restrict__ ea,
                            const int* __restrict__ rowptr, const float* __restrict__ invdeg,
                            int* __restrict__ fillcnt, int* __restrict__ epk,
                            float* __restrict__ escale) {
    int e = blockIdx.x * blockDim.x + threadIdx.x;
    if (e >= NE) return;
    int src = ei[e];
    int dst = ei[NE + e];
    int r = ea[e];
    int pos = atomicAdd(&fillcnt[dst], 1);
    int slot = rowptr[dst] + pos;
    epk[slot] = src | (r << 20);
    escale[slot] = invdeg[(size_t)dst * RELS + r];
}

// ---------------- MFMA GEMM, 2D grid: blockIdx.x = 128-row stripe, blockIdx.y = n-tile (0..8)
// 128x128 tile, BK=64, 256 thr = 4 waves, each wave 64x64 via 16x16x32 bf16 MFMA.
// n-tile 0 -> hnb bf16 (+bias); tiles 1..8 -> xwb fp8.
__global__ __launch_bounds__(256) void gemm_mfma(const unsigned short* __restrict__ habf,
                                                 const unsigned short* __restrict__ wT,
                                                 const float* __restrict__ bias,
                                                 unsigned short* __restrict__ hnb,
                                                 unsigned char* __restrict__ xwb) {
    __shared__ __align__(16) unsigned short As[128][72];   // +8 pad
    __shared__ __align__(16) unsigned short Bs[128][72];
    int tid = threadIdx.x;
    int wave = tid >> 6, lane = tid & 63;
    int wm = (wave & 1) * 64, wn = (wave >> 1) * 64;
    int quad = lane >> 4, l16 = lane & 15;
    int row0 = blockIdx.x * 128;
    int n0 = blockIdx.y;

    f32x4 acc[4][4];
#pragma unroll
    for (int i = 0; i < 4; ++i)
#pragma unroll
        for (int j = 0; j < 4; ++j) acc[i][j] = (f32x4){0.f, 0.f, 0.f, 0.f};

    int srow = tid >> 1;          // 0..127
    int shalf = (tid & 1) * 32;   // 0 / 32 (bf16 elems)
    for (int k0 = 0; k0 < HID; k0 += 64) {
        int grow = row0 + srow;
        const uint4* ga = (const uint4*)(habf + (size_t)grow * HID + k0 + shalf);
        const uint4* gb = (const uint4*)(wT + (size_t)(n0 * 128 + srow) * HID + k0 + shalf);
        uint4 z = {0u, 0u, 0u, 0u};
#pragma unroll
        for (int c = 0; c < 4; ++c) {
            *(uint4*)&As[srow][shalf + c * 8] = (grow < NN) ? ga[c] : z;
            *(uint4*)&Bs[srow][shalf + c * 8] = gb[c];
        }
        __syncthreads();
#pragma unroll
        for (int kc = 0; kc < 2; ++kc) {
            int ko = kc * 32 + quad * 8;
            short8 a[4], b[4];
#pragma unroll
            for (int i = 0; i < 4; ++i) {
                a[i] = *(const short8*)&As[wm + i * 16 + l16][ko];
                b[i] = *(const short8*)&Bs[wn + i * 16 + l16][ko];
            }
#pragma unroll
            for (int i = 0; i < 4; ++i)
#pragma unroll
                for (int j = 0; j < 4; ++j)
                    acc[i][j] = __builtin_amdgcn_mfma_f32_16x16x32_bf16(a[i], b[j], acc[i][j], 0, 0, 0);
        }
        __syncthreads();
    }

    // epilogue (C/D: col=lane&15, row=quad*4+reg)
    if (n0 == 0) {
#pragma unroll
        for (int i = 0; i < 4; ++i)
#pragma unroll
            for (int reg = 0; reg < 4; ++reg) {
                int grow = row0 + wm + i * 16 + quad * 4 + reg;
                if (grow >= NN) continue;
#pragma unroll
                for (int j = 0; j < 4; ++j) {
                    int col = wn + j * 16 + l16;
                    hnb[(size_t)grow * HID + col] = f2bf(acc[i][j][reg] + bias[col]);
                }
            }
    } else {
        int cbase = (n0 - 1) * 128;
#pragma unroll
        for (int i = 0; i < 4; ++i)
#pragma unroll
            for (int reg = 0; reg < 4; ++reg) {
                int grow = row0 + wm + i * 16 + quad * 4 + reg;
                if (grow >= NN) continue;
#pragma unroll
                for (int j = 0; j < 4; ++j) {
                    int col = wn + j * 16 + l16;
                    xwb[(size_t)grow * (RELS * HID) + cbase + col] = f2fp8(acc[i][j][reg]);
                }
            }
    }
}

// ---------------- aggregate (atomic-free): one wave per dst node, edge prefetch + shfl
// habf[dst] = bf16(relu(hnb[dst] + sum_edges fp8(xwb[src][r]) * escale))
__global__ __launch_bounds__(256) void aggregate_kernel(const int* __restrict__ rowptr,
                                                        const int* __restrict__ epk,
                                                        const float* __restrict__ escale,
                                                        const unsigned char* __restrict__ xwb,
                                                        const unsigned short* __restrict__ hnb,
                                                        unsigned short* __restrict__ habf) {
    int node = (blockIdx.x << 2) + (threadIdx.x >> 6);
    if (node >= NN) return;
    int lane = threadIdx.x & 63;
    int beg = rowptr[node], end = rowptr[node + 1];
    float ax = 0.f, ay = 0.f;
    for (int b0 = beg; b0 < end; b0 += 64) {
        int cnt = min(64, end - b0);
        int myp = 0; float mys = 0.f;
        if (lane < cnt) { myp = epk[b0 + lane]; mys = escale[b0 + lane]; }
        int j = 0;
        for (; j + 4 <= cnt; j += 4) {
            int p0 = __shfl(myp, j),     p1 = __shfl(myp, j + 1);
            int p2 = __shfl(myp, j + 2), p3 = __shfl(myp, j + 3);
            float s0 = __shfl(mys, j),     s1 = __shfl(mys, j + 1);
            float s2 = __shfl(mys, j + 2), s3 = __shfl(mys, j + 3);
            unsigned short u0 = *(const unsigned short*)(xwb + (size_t)(p0 & 0xFFFFF) * (RELS * HID) + (p0 >> 20) * HID + lane * 2);
            unsigned short u1 = *(const unsigned short*)(xwb + (size_t)(p1 & 0xFFFFF) * (RELS * HID) + (p1 >> 20) * HID + lane * 2);
            unsigned short u2 = *(const unsigned short*)(xwb + (size_t)(p2 & 0xFFFFF) * (RELS * HID) + (p2 >> 20) * HID + lane * 2);
            unsigned short u3 = *(const unsigned short*)(xwb + (size_t)(p3 & 0xFFFFF) * (RELS * HID) + (p3 >> 20) * HID + lane * 2);
            f32x2 v0 = fp8x2_2f(u0), v1 = fp8x2_2f(u1), v2 = fp8x2_2f(u2), v3 = fp8x2_2f(u3);
            ax += v0.x * s0 + v1.x * s1 + v2.x * s2 + v3.x * s3;
            ay += v0.y * s0 + v1.y * s1 + v2.y * s2 + v3.y * s3;
        }
        for (; j < cnt; ++j) {
            int p = __shfl(myp, j);
            float s = __shfl(mys, j);
            unsigned short u = *(const unsigned short*)(xwb + (size_t)(p & 0xFFFFF) * (RELS * HID) + (p >> 20) * HID + lane * 2);
            f32x2 v = fp8x2_2f(u);
            ax += v.x * s;
            ay += v.y * s;
        }
    }
    ushort2 cu = *((const ushort2*)(hnb + (size_t)node * HID) + lane);
    ushort2 o;
    o.x = f2bf(fmaxf(bf2f(cu.x) + ax, 0.f));
    o.y = f2bf(fmaxf(bf2f(cu.y) + ay, 0.f));
    *((ushort2*)(habf + (size_t)node * HID) + lane) = o;
}

// ---------------- global mean pool: sorted-batch register accumulation, flush on g-change
__global__ __launch_bounds__(256) void pool_kernel(const unsigned short* __restrict__ habf,
                                                   const int* __restrict__ batch,
                                                   float* __restrict__ psum,
                                                   float* __restrict__ pcnt) {
    int tid = threadIdx.x;
    int f = tid & 127;
    int sub = tid >> 7;
    int base = blockIdx.x * PCHUNK;
    float acc = 0.f, cnt = 0.f;
    int gcur = -1;
    for (int it = 0; it < PCHUNK / 2; ++it) {
        int node = base + it * 2 + sub;
        if (node >= NN) break;
        int g = batch[node];
        if (g != gcur) {
            if (gcur >= 0) {
                atomicAdd(&psum[gcur * HID + f], acc);
                if (f == 0) atomicAdd(&pcnt[gcur], cnt);
            }
            gcur = g; acc = 0.f; cnt = 0.f;
        }
        acc += bf2f(habf[(size_t)node * HID + f]);
        cnt += 1.f;
    }
    if (gcur >= 0) {
        atomicAdd(&psum[gcur * HID + f], acc);
        if (f == 0) atomicAdd(&pcnt[gcur], cnt);
    }
}

// ---------------- head
__global__ void head_kernel(const float* __restrict__ psum, const float* __restrict__ pcnt,
                            const float* __restrict__ g2, const float* __restrict__ b2,
                            const float* __restrict__ m2, const float* __restrict__ v2,
                            const float* __restrict__ fc1w, const float* __restrict__ fc1b,
                            const float* __restrict__ fc2w, const float* __restrict__ fc2b,
                            float* __restrict__ out) {
    __shared__ float v[HID];
    __shared__ float u[HID];
    __shared__ float lg[CLASSES];
    int j = threadIdx.x;
    float acc = 0.f;
    for (int g = 0; g < GRAPHS; ++g) {
        float val = psum[g * HID + j] / fmaxf(pcnt[g], 1.0f);
        val = (val - m2[j]) * rsqrtf(v2[j] + EPSV) * g2[j] + b2[j];
        acc += val;
    }
    v[j] = fmaxf(acc / (float)GRAPHS, 0.f);
    __syncthreads();
    float s = fc1b[j];
    for (int k = 0; k < HID; ++k) s += v[k] * fc1w[k * HID + j];
    u[j] = fmaxf(s, 0.f);
    __syncthreads();
    if (j < CLASSES) {
        float t = fc2b[j];
        for (int k = 0; k < HID; ++k) t += u[k] * fc2w[k * CLASSES + j];
        lg[j] = t;
    }
    __syncthreads();
    if (j < CLASSES) {
        float mx = lg[0];
        for (int c = 1; c < CLASSES; ++c) mx = fmaxf(mx, lg[c]);
        float se = 0.f;
        for (int c = 0; c < CLASSES; ++c) se += expf(lg[c] - mx);
        out[j] = lg[j] - mx - logf(se);
    }
}

extern "C" void kernel_launch(void* const* d_in, const int* in_sizes, int n_in,
                              void* d_out, int out_size, void* d_ws, size_t ws_size,
                              hipStream_t stream) {
    const float* x     = (const float*)d_in[0];
    const int*   ei    = (const int*)d_in[1];
    const int*   ea    = (const int*)d_in[2];
    const int*   batch = (const int*)d_in[3];
    const float* bn1g  = (const float*)d_in[4];
    const float* bn1b  = (const float*)d_in[5];
    const float* bn1m  = (const float*)d_in[6];
    const float* bn1v  = (const float*)d_in[7];
    const float* basis = (const float*)d_in[8];
    const float* comp  = (const float*)d_in[9];
    const float* root  = (const float*)d_in[10];
    const float* bias  = (const float*)d_in[11];
    const float* bn2g  = (const float*)d_in[12];
    const float* bn2b  = (const float*)d_in[13];
    const float* bn2m  = (const float*)d_in[14];
    const float* bn2v  = (const float*)d_in[15];
    const float* fc1w  = (const float*)d_in[16];
    const float* fc1b  = (const float*)d_in[17];
    const float* fc2w  = (const float*)d_in[18];
    const float* fc2b  = (const float*)d_in[19];

    float* ws = (float*)d_ws;
    size_t off = 0;
    unsigned short* wT = (unsigned short*)(ws + off); off += (size_t)LAYERS * NOUT * HID / 2;
    unsigned short* hnb  = (unsigned short*)(ws + off); off += (size_t)NN * HID / 2;
    unsigned short* habf = (unsigned short*)(ws + off); off += (size_t)NN * HID / 2;
    float* deg    = ws + off; off += (size_t)NN * RELS;
    float* psum   = ws + off; off += (size_t)GRAPHS * HID + GRAPHS;
    float* pcnt   = psum + GRAPHS * HID;
    float* escale = ws + off; off += (size_t)NE;
    int* degi     = (int*)(ws + off); off += (size_t)NN;
    int* rowptr   = (int*)(ws + off); off += (size_t)NN + 1;
    int* fillcnt  = (int*)(ws + off); off += (size_t)NN;
    int* bsum     = (int*)(ws + off); off += (size_t)SCAN_NBLK;
    int* epk      = (int*)(ws + off); off += (size_t)NE;
    off = (off + 3) & ~(size_t)3;
    unsigned char* xwb = (unsigned char*)(ws + off);
    off += (size_t)NN * RELS * HID / 4;                 // fp8: 51.2 MB
    if (ws_size < off * sizeof(float)) return;

    hipMemsetAsync(psum, 0, (GRAPHS * HID + GRAPHS) * sizeof(float), stream);
    hipMemsetAsync(deg, 0, (size_t)NN * RELS * sizeof(float), stream);
    hipMemsetAsync(fillcnt, 0, (size_t)NN * sizeof(int), stream);

    build_wcat<<<LAYERS * 64, 256, 0, stream>>>(basis, comp, root, wT);
    bn1_kernel<<<(NN * HID + 255) / 256, 256, 0, stream>>>(x, bn1g, bn1b, bn1m, bn1v, habf);

    deg_kernel<<<(NE + 255) / 256, 256, 0, stream>>>(ei, ea, deg);
    invdeg_kernel<<<(NN + 255) / 256, 256, 0, stream>>>(deg, degi);
    scan_partial<<<SCAN_NBLK, 256, 0, stream>>>(degi, rowptr, bsum);
    scan_bsum<<<1, 64, 0, stream>>>(bsum);
    scan_add<<<(NN + 255) / 256, 256, 0, stream>>>(rowptr, bsum);
    fill_kernel<<<(NE + 255) / 256, 256, 0, stream>>>(ei, ea, rowptr, deg, fillcnt, epk, escale);

    dim3 ggrid((NN + 127) / 128, RELS + 1);
    for (int l = 0; l < LAYERS; ++l) {
        gemm_mfma<<<ggrid, 256, 0, stream>>>(habf, wT + (size_t)l * NOUT * HID,
                                             bias + (size_t)l * HID, hnb, xwb);
        aggregate_kernel<<<(NN + 3) / 4, 256, 0, stream>>>(rowptr, epk, escale, xwb, hnb, habf);
    }

    pool_kernel<<<(NN + PCHUNK - 1) / PCHUNK, 256, 0, stream>>>(habf, batch, psum, pcnt);
    head_kernel<<<1, 128, 0, stream>>>(psum, pcnt, bn2g, bn2b, bn2m, bn2v,
                                       fc1w, fc1b, fc2w, fc2b, (float*)d_out);
}

// Round 12
// 458.945 us; speedup vs baseline: 1.0739x; 1.0191x over previous
//
#include <hip/hip_runtime.h>
#include <hip/hip_bf16.h>

#define NN 50000
#define NE 500000
#define HID 128
#define LAYERS 3
#define RELS 8
#define BASES 30
#define GRAPHS 16
#define CLASSES 8
#define EPSV 1e-5f
#define NOUT (HID * (RELS + 1))   // 1152
#define SCAN_CHUNK 1024
#define SCAN_NBLK ((NN + SCAN_CHUNK - 1) / SCAN_CHUNK)   // 49
#define PCHUNK 128

typedef __attribute__((ext_vector_type(8))) short short8;   // 8 bf16 (4 VGPRs)
typedef __attribute__((ext_vector_type(4))) float f32x4;    // MFMA accumulator
typedef __attribute__((ext_vector_type(2))) float f32x2;

__device__ __forceinline__ float bf2f(unsigned short u) {
    union { unsigned int i; float f; } x; x.i = ((unsigned int)u) << 16; return x.f;
}
__device__ __forceinline__ unsigned short f2bf(float f) {
    __hip_bfloat16 b = __float2bfloat16(f);
    return *(unsigned short*)&b;
}
__device__ __forceinline__ f32x2 fp8x2_2f(unsigned short u) {
    return __builtin_amdgcn_cvt_pk_f32_fp8((int)u, false);
}
// storage permutation: feature f lives at in-row position perm(f).
// perm maps thread fragment cols {wn + j*16 + l16} -> consecutive {wn + l16*4 + j}.
__device__ __forceinline__ int permf(int f) {
    return (f & 64) | ((f & 15) << 2) | ((f >> 4) & 3);
}
__device__ __forceinline__ int ipermf(int q) {
    return (q & 64) | ((q & 3) << 4) | ((q >> 2) & 15);
}

// ---------------- wT: [L][1152 n][128 k] bf16, k stored at perm(k)
__global__ __launch_bounds__(256) void build_wcat(const float* __restrict__ basis,
                                                  const float* __restrict__ comp,
                                                  const float* __restrict__ root,
                                                  unsigned short* __restrict__ wT) {
    int bid = blockIdx.x;
    int l = bid >> 6;               // 0..2
    int k0 = (bid & 63) << 1;       // 0,2,..,126
    __shared__ float cl[RELS * BASES];   // 240
    int tid = threadIdx.x;
    if (tid < RELS * BASES) cl[tid] = comp[l * RELS * BASES + tid];
    __syncthreads();
    int j = tid & 127;
    int k = k0 + (tid >> 7);
    int pk = permf(k);
    const float* bp = basis + ((size_t)l * BASES * HID + k) * HID + j;
    float acc[RELS];
#pragma unroll
    for (int r = 0; r < RELS; ++r) acc[r] = 0.f;
    for (int b = 0; b < BASES; ++b) {
        float v = bp[(size_t)b * HID * HID];
#pragma unroll
        for (int r = 0; r < RELS; ++r) acc[r] += cl[r * BASES + b] * v;
    }
    unsigned short* wl = wT + (size_t)l * NOUT * HID;
#pragma unroll
    for (int r = 0; r < RELS; ++r)
        wl[(size_t)((1 + r) * HID + j) * HID + pk] = f2bf(acc[r]);
    // root columns: wT[l][j][perm(k)] = root[l][k][j]
    wl[(size_t)j * HID + pk] = f2bf(root[((size_t)l * HID + k) * HID + j]);
}

// ---------------- BN1 (eval mode) -> bf16, permuted feature storage
__global__ void bn1_kernel(const float* __restrict__ x, const float* __restrict__ gamma,
                           const float* __restrict__ beta, const float* __restrict__ mean,
                           const float* __restrict__ var, unsigned short* __restrict__ habf) {
    int idx = blockIdx.x * blockDim.x + threadIdx.x;
    if (idx >= NN * HID) return;
    int q = idx & (HID - 1);
    int n = idx >> 7;
    int f = ipermf(q);
    habf[idx] = f2bf((x[(n << 7) + f] - mean[f]) * rsqrtf(var[f] + EPSV) * gamma[f] + beta[f]);
}

// ---------------- degree count per (dst, rel)
__global__ void deg_kernel(const int* __restrict__ ei, const int* __restrict__ ea,
                           float* __restrict__ deg) {
    int e = blockIdx.x * blockDim.x + threadIdx.x;
    if (e >= NE) return;
    int dst = ei[NE + e];
    atomicAdd(&deg[(size_t)dst * RELS + ea[e]], 1.0f);
}

// degi = int total degree; deg -> invdeg in-place
__global__ void invdeg_kernel(float* __restrict__ deg, int* __restrict__ degi) {
    int n = blockIdx.x * blockDim.x + threadIdx.x;
    if (n >= NN) return;
    float s = 0.f;
#pragma unroll
    for (int r = 0; r < RELS; ++r) {
        float d = deg[(size_t)n * RELS + r];
        s += d;
        deg[(size_t)n * RELS + r] = 1.0f / fmaxf(d, 1.0f);
    }
    degi[n] = (int)(s + 0.5f);
}

// ---------------- exclusive scan of degi -> rowptr
__global__ __launch_bounds__(256) void scan_partial(const int* __restrict__ degi,
                                                    int* __restrict__ rowptr,
                                                    int* __restrict__ bsum) {
    __shared__ int ssc[256];
    int t = threadIdx.x;
    int base = blockIdx.x * SCAN_CHUNK + t * 4;
    int v[4];
#pragma unroll
    for (int j = 0; j < 4; ++j) v[j] = (base + j < NN) ? degi[base + j] : 0;
    int tsum = v[0] + v[1] + v[2] + v[3];
    ssc[t] = tsum;
    __syncthreads();
    for (int ofs = 1; ofs < 256; ofs <<= 1) {
        int add = (t >= ofs) ? ssc[t - ofs] : 0;
        __syncthreads();
        ssc[t] += add;
        __syncthreads();
    }
    int excl = ssc[t] - tsum;
    int e = 0;
#pragma unroll
    for (int j = 0; j < 4; ++j) {
        if (base + j < NN) rowptr[base + j] = excl + e;
        e += v[j];
    }
    if (t == 255) bsum[blockIdx.x] = ssc[255];
}

__global__ void scan_bsum(int* __restrict__ bsum) {
    if (threadIdx.x == 0) {
        int acc = 0;
        for (int b = 0; b < SCAN_NBLK; ++b) { int v = bsum[b]; bsum[b] = acc; acc += v; }
    }
}

__global__ __launch_bounds__(256) void scan_add(int* __restrict__ rowptr,
                                                const int* __restrict__ bsum) {
    int i = blockIdx.x * blockDim.x + threadIdx.x;
    if (i < NN) rowptr[i] += bsum[i >> 10];
    if (i == 0) rowptr[NN] = NE;
}

// ---------------- fill CSR
__global__ void fill_kernel(const int* __restrict__ ei, const int* __restrict__ ea,
                            const int* __restrict__ rowptr, const float* __restrict__ invdeg,
                            int* __restrict__ fillcnt, int* __restrict__ epk,
                            float* __restrict__ escale) {
    int e = blockIdx.x * blockDim.x + threadIdx.x;
    if (e >= NE) return;
    int src = ei[e];
    int dst = ei[NE + e];
    int r = ea[e];
    int pos = atomicAdd(&fillcnt[dst], 1);
    int slot = rowptr[dst] + pos;
    epk[slot] = src | (r << 20);
    escale[slot] = invdeg[(size_t)dst * RELS + r];
}

// ---------------- MFMA GEMM, 1D grid y-fastest: bid = stripe*9 + n0 (9 consecutive
// blocks share the A stripe -> L2 locality). 128x128 tile, BK=64, 4 waves.
// n-tile 0 -> hnb bf16 (+bias); tiles 1..8 -> xwb fp8. Outputs stored permuted (packed stores).
__global__ __launch_bounds__(256) void gemm_mfma(const unsigned short* __restrict__ habf,
                                                 const unsigned short* __restrict__ wT,
                                                 const float* __restrict__ bias,
                                                 unsigned short* __restrict__ hnb,
                                                 unsigned char* __restrict__ xwb) {
    __shared__ __align__(16) unsigned short As[128][72];   // +8 pad
    __shared__ __align__(16) unsigned short Bs[128][72];
    int tid = threadIdx.x;
    int wave = tid >> 6, lane = tid & 63;
    int wm = (wave & 1) * 64, wn = (wave >> 1) * 64;
    int quad = lane >> 4, l16 = lane & 15;
    int n0 = blockIdx.x % (RELS + 1);
    int row0 = (blockIdx.x / (RELS + 1)) * 128;

    f32x4 acc[4][4];
#pragma unroll
    for (int i = 0; i < 4; ++i)
#pragma unroll
        for (int j = 0; j < 4; ++j) acc[i][j] = (f32x4){0.f, 0.f, 0.f, 0.f};

    int srow = tid >> 1;          // 0..127
    int shalf = (tid & 1) * 32;   // 0 / 32 (bf16 elems)
    for (int k0 = 0; k0 < HID; k0 += 64) {
        int grow = row0 + srow;
        const uint4* ga = (const uint4*)(habf + (size_t)grow * HID + k0 + shalf);
        const uint4* gb = (const uint4*)(wT + (size_t)(n0 * 128 + srow) * HID + k0 + shalf);
        uint4 z = {0u, 0u, 0u, 0u};
#pragma unroll
        for (int c = 0; c < 4; ++c) {
            *(uint4*)&As[srow][shalf + c * 8] = (grow < NN) ? ga[c] : z;
            *(uint4*)&Bs[srow][shalf + c * 8] = gb[c];
        }
        __syncthreads();
#pragma unroll
        for (int kc = 0; kc < 2; ++kc) {
            int ko = kc * 32 + quad * 8;
            short8 a[4], b[4];
#pragma unroll
            for (int i = 0; i < 4; ++i) {
                a[i] = *(const short8*)&As[wm + i * 16 + l16][ko];
                b[i] = *(const short8*)&Bs[wn + i * 16 + l16][ko];
            }
#pragma unroll
            for (int i = 0; i < 4; ++i)
#pragma unroll
                for (int j = 0; j < 4; ++j)
                    acc[i][j] = __builtin_amdgcn_mfma_f32_16x16x32_bf16(a[i], b[j], acc[i][j], 0, 0, 0);
        }
        __syncthreads();
    }

    // epilogue (C/D: col=lane&15, row=quad*4+reg); packed stores at permuted positions
    int pbase = wn + l16 * 4;
    if (n0 == 0) {
#pragma unroll
        for (int i = 0; i < 4; ++i)
#pragma unroll
            for (int reg = 0; reg < 4; ++reg) {
                int grow = row0 + wm + i * 16 + quad * 4 + reg;
                if (grow >= NN) continue;
                unsigned lo = (unsigned)f2bf(acc[i][0][reg] + bias[wn + l16]) |
                              ((unsigned)f2bf(acc[i][1][reg] + bias[wn + 16 + l16]) << 16);
                unsigned hi = (unsigned)f2bf(acc[i][2][reg] + bias[wn + 32 + l16]) |
                              ((unsigned)f2bf(acc[i][3][reg] + bias[wn + 48 + l16]) << 16);
                uint2 pk = {lo, hi};
                *(uint2*)(hnb + (size_t)grow * HID + pbase) = pk;
            }
    } else {
        int cbase = (n0 - 1) * 128;
#pragma unroll
        for (int i = 0; i < 4; ++i)
#pragma unroll
            for (int reg = 0; reg < 4; ++reg) {
                int grow = row0 + wm + i * 16 + quad * 4 + reg;
                if (grow >= NN) continue;
                unsigned w = (unsigned)__builtin_amdgcn_cvt_pk_fp8_f32(acc[i][0][reg], acc[i][1][reg], 0, false);
                w = (unsigned)__builtin_amdgcn_cvt_pk_fp8_f32(acc[i][2][reg], acc[i][3][reg], (int)w, true);
                *(unsigned*)(xwb + (size_t)grow * (RELS * HID) + cbase + pbase) = w;
            }
    }
}

// ---------------- aggregate (atomic-free): one wave per dst node, edge prefetch + shfl
// position-wise (permutation-transparent): habf[dst] = relu(hnb[dst] + sum xwb[src][r]*s)
__global__ __launch_bounds__(256) void aggregate_kernel(const int* __restrict__ rowptr,
                                                        const int* __restrict__ epk,
                                                        const float* __restrict__ escale,
                                                        const unsigned char* __restrict__ xwb,
                                                        const unsigned short* __restrict__ hnb,
                                                        unsigned short* __restrict__ habf) {
    int node = (blockIdx.x << 2) + (threadIdx.x >> 6);
    if (node >= NN) return;
    int lane = threadIdx.x & 63;
    int beg = rowptr[node], end = rowptr[node + 1];
    float ax = 0.f, ay = 0.f;
    for (int b0 = beg; b0 < end; b0 += 64) {
        int cnt = min(64, end - b0);
        int myp = 0; float mys = 0.f;
        if (lane < cnt) { myp = epk[b0 + lane]; mys = escale[b0 + lane]; }
        int j = 0;
        for (; j + 4 <= cnt; j += 4) {
            int p0 = __shfl(myp, j),     p1 = __shfl(myp, j + 1);
            int p2 = __shfl(myp, j + 2), p3 = __shfl(myp, j + 3);
            float s0 = __shfl(mys, j),     s1 = __shfl(mys, j + 1);
            float s2 = __shfl(mys, j + 2), s3 = __shfl(mys, j + 3);
            unsigned short u0 = *(const unsigned short*)(xwb + (size_t)(p0 & 0xFFFFF) * (RELS * HID) + (p0 >> 20) * HID + lane * 2);
            unsigned short u1 = *(const unsigned short*)(xwb + (size_t)(p1 & 0xFFFFF) * (RELS * HID) + (p1 >> 20) * HID + lane * 2);
            unsigned short u2 = *(const unsigned short*)(xwb + (size_t)(p2 & 0xFFFFF) * (RELS * HID) + (p2 >> 20) * HID + lane * 2);
            unsigned short u3 = *(const unsigned short*)(xwb + (size_t)(p3 & 0xFFFFF) * (RELS * HID) + (p3 >> 20) * HID + lane * 2);
            f32x2 v0 = fp8x2_2f(u0), v1 = fp8x2_2f(u1), v2 = fp8x2_2f(u2), v3 = fp8x2_2f(u3);
            ax += v0.x * s0 + v1.x * s1 + v2.x * s2 + v3.x * s3;
            ay += v0.y * s0 + v1.y * s1 + v2.y * s2 + v3.y * s3;
        }
        for (; j < cnt; ++j) {
            int p = __shfl(myp, j);
            float s = __shfl(mys, j);
            unsigned short u = *(const unsigned short*)(xwb + (size_t)(p & 0xFFFFF) * (RELS * HID) + (p >> 20) * HID + lane * 2);
            f32x2 v = fp8x2_2f(u);
            ax += v.x * s;
            ay += v.y * s;
        }
    }
    ushort2 cu = *((const ushort2*)(hnb + (size_t)node * HID) + lane);
    ushort2 o;
    o.x = f2bf(fmaxf(bf2f(cu.x) + ax, 0.f));
    o.y = f2bf(fmaxf(bf2f(cu.y) + ay, 0.f));
    *((ushort2*)(habf + (size_t)node * HID) + lane) = o;
}

// ---------------- global mean pool: sorted-batch register accumulation (position-wise)
__global__ __launch_bounds__(256) void pool_kernel(const unsigned short* __restrict__ habf,
                                                   const int* __restrict__ batch,
                                                   float* __restrict__ psum,
                                                   float* __restrict__ pcnt) {
    int tid = threadIdx.x;
    int f = tid & 127;
    int sub = tid >> 7;
    int base = blockIdx.x * PCHUNK;
    float acc = 0.f, cnt = 0.f;
    int gcur = -1;
    for (int it = 0; it < PCHUNK / 2; ++it) {
        int node = base + it * 2 + sub;
        if (node >= NN) break;
        int g = batch[node];
        if (g != gcur) {
            if (gcur >= 0) {
                atomicAdd(&psum[gcur * HID + f], acc);
                if (f == 0) atomicAdd(&pcnt[gcur], cnt);
            }
            gcur = g; acc = 0.f; cnt = 0.f;
        }
        acc += bf2f(habf[(size_t)node * HID + f]);
        cnt += 1.f;
    }
    if (gcur >= 0) {
        atomicAdd(&psum[gcur * HID + f], acc);
        if (f == 0) atomicAdd(&pcnt[gcur], cnt);
    }
}

// ---------------- head (unpermutes psum)
__global__ void head_kernel(const float* __restrict__ psum, const float* __restrict__ pcnt,
                            const float* __restrict__ g2, const float* __restrict__ b2,
                            const float* __restrict__ m2, const float* __restrict__ v2,
                            const float* __restrict__ fc1w, const float* __restrict__ fc1b,
                            const float* __restrict__ fc2w, const float* __restrict__ fc2b,
                            float* __restrict__ out) {
    __shared__ float v[HID];
    __shared__ float u[HID];
    __shared__ float lg[CLASSES];
    int j = threadIdx.x;
    int pj = permf(j);
    float acc = 0.f;
    for (int g = 0; g < GRAPHS; ++g) {
        float val = psum[g * HID + pj] / fmaxf(pcnt[g], 1.0f);
        val = (val - m2[j]) * rsqrtf(v2[j] + EPSV) * g2[j] + b2[j];
        acc += val;
    }
    v[j] = fmaxf(acc / (float)GRAPHS, 0.f);
    __syncthreads();
    float s = fc1b[j];
    for (int k = 0; k < HID; ++k) s += v[k] * fc1w[k * HID + j];
    u[j] = fmaxf(s, 0.f);
    __syncthreads();
    if (j < CLASSES) {
        float t = fc2b[j];
        for (int k = 0; k < HID; ++k) t += u[k] * fc2w[k * CLASSES + j];
        lg[j] = t;
    }
    __syncthreads();
    if (j < CLASSES) {
        float mx = lg[0];
        for (int c = 1; c < CLASSES; ++c) mx = fmaxf(mx, lg[c]);
        float se = 0.f;
        for (int c = 0; c < CLASSES; ++c) se += expf(lg[c] - mx);
        out[j] = lg[j] - mx - logf(se);
    }
}

extern "C" void kernel_launch(void* const* d_in, const int* in_sizes, int n_in,
                              void* d_out, int out_size, void* d_ws, size_t ws_size,
                              hipStream_t stream) {
    const float* x     = (const float*)d_in[0];
    const int*   ei    = (const int*)d_in[1];
    const int*   ea    = (const int*)d_in[2];
    const int*   batch = (const int*)d_in[3];
    const float* bn1g  = (const float*)d_in[4];
    const float* bn1b  = (const float*)d_in[5];
    const float* bn1m  = (const float*)d_in[6];
    const float* bn1v  = (const float*)d_in[7];
    const float* basis = (const float*)d_in[8];
    const float* comp  = (const float*)d_in[9];
    const float* root  = (const float*)d_in[10];
    const float* bias  = (const float*)d_in[11];
    const float* bn2g  = (const float*)d_in[12];
    const float* bn2b  = (const float*)d_in[13];
    const float* bn2m  = (const float*)d_in[14];
    const float* bn2v  = (const float*)d_in[15];
    const float* fc1w  = (const float*)d_in[16];
    const float* fc1b  = (const float*)d_in[17];
    const float* fc2w  = (const float*)d_in[18];
    const float* fc2b  = (const float*)d_in[19];

    float* ws = (float*)d_ws;
    size_t off = 0;
    unsigned short* wT = (unsigned short*)(ws + off); off += (size_t)LAYERS * NOUT * HID / 2;
    unsigned short* hnb  = (unsigned short*)(ws + off); off += (size_t)NN * HID / 2;
    unsigned short* habf = (unsigned short*)(ws + off); off += (size_t)NN * HID / 2;
    float* deg    = ws + off; off += (size_t)NN * RELS;
    float* psum   = ws + off; off += (size_t)GRAPHS * HID + GRAPHS;
    float* pcnt   = psum + GRAPHS * HID;
    float* escale = ws + off; off += (size_t)NE;
    int* degi     = (int*)(ws + off); off += (size_t)NN;
    int* rowptr   = (int*)(ws + off); off += (size_t)NN + 1;
    int* fillcnt  = (int*)(ws + off); off += (size_t)NN;
    int* bsum     = (int*)(ws + off); off += (size_t)SCAN_NBLK;
    int* epk      = (int*)(ws + off); off += (size_t)NE;
    off = (off + 3) & ~(size_t)3;
    unsigned char* xwb = (unsigned char*)(ws + off);
    off += (size_t)NN * RELS * HID / 4;                 // fp8: 51.2 MB
    if (ws_size < off * sizeof(float)) return;

    hipMemsetAsync(psum, 0, (GRAPHS * HID + GRAPHS) * sizeof(float), stream);
    hipMemsetAsync(deg, 0, (size_t)NN * RELS * sizeof(float), stream);
    hipMemsetAsync(fillcnt, 0, (size_t)NN * sizeof(int), stream);

    build_wcat<<<LAYERS * 64, 256, 0, stream>>>(basis, comp, root, wT);
    bn1_kernel<<<(NN * HID + 255) / 256, 256, 0, stream>>>(x, bn1g, bn1b, bn1m, bn1v, habf);

    deg_kernel<<<(NE + 255) / 256, 256, 0, stream>>>(ei, ea, deg);
    invdeg_kernel<<<(NN + 255) / 256, 256, 0, stream>>>(deg, degi);
    scan_partial<<<SCAN_NBLK, 256, 0, stream>>>(degi, rowptr, bsum);
    scan_bsum<<<1, 64, 0, stream>>>(bsum);
    scan_add<<<(NN + 255) / 256, 256, 0, stream>>>(rowptr, bsum);
    fill_kernel<<<(NE + 255) / 256, 256, 0, stream>>>(ei, ea, rowptr, deg, fillcnt, epk, escale);

    int gblocks = ((NN + 127) / 128) * (RELS + 1);
    for (int l = 0; l < LAYERS; ++l) {
        gemm_mfma<<<gblocks, 256, 0, stream>>>(habf, wT + (size_t)l * NOUT * HID,
                                               bias + (size_t)l * HID, hnb, xwb);
        aggregate_kernel<<<(NN + 3) / 4, 256, 0, stream>>>(rowptr, epk, escale, xwb, hnb, habf);
    }

    pool_kernel<<<(NN + PCHUNK - 1) / PCHUNK, 256, 0, stream>>>(habf, batch, psum, pcnt);
    head_kernel<<<1, 128, 0, stream>>>(psum, pcnt, bn2g, bn2b, bn2m, bn2v,
                                       fc1w, fc1b, fc2w, fc2b, (float*)d_out);
}

// Round 14
// 431.103 us; speedup vs baseline: 1.1432x; 1.0646x over previous
//
#include <hip/hip_runtime.h>
#include <hip/hip_bf16.h>

#define NN 50000
#define NE 500000
#define HID 128
#define LAYERS 3
#define RELS 8
#define BASES 30
#define GRAPHS 16
#define CLASSES 8
#define EPSV 1e-5f
#define NOUT (HID * (RELS + 1))   // 1152
#define SCAN_CHUNK 1024
#define SCAN_NBLK ((NN + SCAN_CHUNK - 1) / SCAN_CHUNK)   // 49
#define PCHUNK 128
#define NSTRIPE ((NN + 127) / 128)                        // 391
#define NSG ((NSTRIPE + 7) / 8)                           // 49 stripe-groups

typedef __attribute__((ext_vector_type(8))) short short8;   // 8 bf16 (4 VGPRs)
typedef __attribute__((ext_vector_type(4))) float f32x4;    // MFMA accumulator
typedef __attribute__((ext_vector_type(2))) float f32x2;

__device__ __forceinline__ float bf2f(unsigned short u) {
    union { unsigned int i; float f; } x; x.i = ((unsigned int)u) << 16; return x.f;
}
__device__ __forceinline__ unsigned short f2bf(float f) {
    __hip_bfloat16 b = __float2bfloat16(f);
    return *(unsigned short*)&b;
}
template <bool HI>
__device__ __forceinline__ f32x2 fp8x2_2f(int u) {
    return __builtin_amdgcn_cvt_pk_f32_fp8(u, HI);   // word-select must be constant
}
// storage permutation: feature f lives at in-row position perm(f).
__device__ __forceinline__ int permf(int f) {
    return (f & 64) | ((f & 15) << 2) | ((f >> 4) & 3);
}
__device__ __forceinline__ int ipermf(int q) {
    return (q & 64) | ((q & 3) << 4) | ((q >> 2) & 15);
}

// ---------------- wT: [L][1152 n][128 k] bf16, k stored at perm(k)
__global__ __launch_bounds__(256) void build_wcat(const float* __restrict__ basis,
                                                  const float* __restrict__ comp,
                                                  const float* __restrict__ root,
                                                  unsigned short* __restrict__ wT) {
    int bid = blockIdx.x;
    int l = bid >> 6;               // 0..2
    int k0 = (bid & 63) << 1;       // 0,2,..,126
    __shared__ float cl[RELS * BASES];   // 240
    int tid = threadIdx.x;
    if (tid < RELS * BASES) cl[tid] = comp[l * RELS * BASES + tid];
    __syncthreads();
    int j = tid & 127;
    int k = k0 + (tid >> 7);
    int pk = permf(k);
    const float* bp = basis + ((size_t)l * BASES * HID + k) * HID + j;
    float acc[RELS];
#pragma unroll
    for (int r = 0; r < RELS; ++r) acc[r] = 0.f;
    for (int b = 0; b < BASES; ++b) {
        float v = bp[(size_t)b * HID * HID];
#pragma unroll
        for (int r = 0; r < RELS; ++r) acc[r] += cl[r * BASES + b] * v;
    }
    unsigned short* wl = wT + (size_t)l * NOUT * HID;
#pragma unroll
    for (int r = 0; r < RELS; ++r)
        wl[(size_t)((1 + r) * HID + j) * HID + pk] = f2bf(acc[r]);
    wl[(size_t)j * HID + pk] = f2bf(root[((size_t)l * HID + k) * HID + j]);
}

// ---------------- BN1 (eval mode) -> bf16, permuted feature storage
__global__ void bn1_kernel(const float* __restrict__ x, const float* __restrict__ gamma,
                           const float* __restrict__ beta, const float* __restrict__ mean,
                           const float* __restrict__ var, unsigned short* __restrict__ habf) {
    int idx = blockIdx.x * blockDim.x + threadIdx.x;
    if (idx >= NN * HID) return;
    int q = idx & (HID - 1);
    int n = idx >> 7;
    int f = ipermf(q);
    habf[idx] = f2bf((x[(n << 7) + f] - mean[f]) * rsqrtf(var[f] + EPSV) * gamma[f] + beta[f]);
}

// ---------------- degree count per (dst, rel)
__global__ void deg_kernel(const int* __restrict__ ei, const int* __restrict__ ea,
                           float* __restrict__ deg) {
    int e = blockIdx.x * blockDim.x + threadIdx.x;
    if (e >= NE) return;
    int dst = ei[NE + e];
    atomicAdd(&deg[(size_t)dst * RELS + ea[e]], 1.0f);
}

// degi = int total degree; deg -> invdeg in-place
__global__ void invdeg_kernel(float* __restrict__ deg, int* __restrict__ degi) {
    int n = blockIdx.x * blockDim.x + threadIdx.x;
    if (n >= NN) return;
    float s = 0.f;
#pragma unroll
    for (int r = 0; r < RELS; ++r) {
        float d = deg[(size_t)n * RELS + r];
        s += d;
        deg[(size_t)n * RELS + r] = 1.0f / fmaxf(d, 1.0f);
    }
    degi[n] = (int)(s + 0.5f);
}

// ---------------- exclusive scan of degi -> rowptr
__global__ __launch_bounds__(256) void scan_partial(const int* __restrict__ degi,
                                                    int* __restrict__ rowptr,
                                                    int* __restrict__ bsum) {
    __shared__ int ssc[256];
    int t = threadIdx.x;
    int base = blockIdx.x * SCAN_CHUNK + t * 4;
    int v[4];
#pragma unroll
    for (int j = 0; j < 4; ++j) v[j] = (base + j < NN) ? degi[base + j] : 0;
    int tsum = v[0] + v[1] + v[2] + v[3];
    ssc[t] = tsum;
    __syncthreads();
    for (int ofs = 1; ofs < 256; ofs <<= 1) {
        int add = (t >= ofs) ? ssc[t - ofs] : 0;
        __syncthreads();
        ssc[t] += add;
        __syncthreads();
    }
    int excl = ssc[t] - tsum;
    int e = 0;
#pragma unroll
    for (int j = 0; j < 4; ++j) {
        if (base + j < NN) rowptr[base + j] = excl + e;
        e += v[j];
    }
    if (t == 255) bsum[blockIdx.x] = ssc[255];
}

__global__ void scan_bsum(int* __restrict__ bsum) {
    if (threadIdx.x == 0) {
        int acc = 0;
        for (int b = 0; b < SCAN_NBLK; ++b) { int v = bsum[b]; bsum[b] = acc; acc += v; }
    }
}

__global__ __launch_bounds__(256) void scan_add(int* __restrict__ rowptr,
                                                const int* __restrict__ bsum) {
    int i = blockIdx.x * blockDim.x + threadIdx.x;
    if (i < NN) rowptr[i] += bsum[i >> 10];
    if (i == 0) rowptr[NN] = NE;
}

// ---------------- fill CSR
__global__ void fill_kernel(const int* __restrict__ ei, const int* __restrict__ ea,
                            const int* __restrict__ rowptr, const float* __restrict__ invdeg,
                            int* __restrict__ fillcnt, int* __restrict__ epk,
                            float* __restrict__ escale) {
    int e = blockIdx.x * blockDim.x + threadIdx.x;
    if (e >= NE) return;
    int src = ei[e];
    int dst = ei[NE + e];
    int r = ea[e];
    int pos = atomicAdd(&fillcnt[dst], 1);
    int slot = rowptr[dst] + pos;
    epk[slot] = src | (r << 20);
    escale[slot] = invdeg[(size_t)dst * RELS + r];
}

// ---------------- MFMA GEMM, XCD-swizzled grid: bid = (g*9 + n0)*8 + (s%8), s = g*8 + s%8.
// All 9 n-tiles of stripe s share bid%8 (same XCD under round-robin) -> A stripe fetched once/XCD.
// n-tile 0 -> hnb bf16 (+bias); tiles 1..8 -> xwb fp8. Outputs permuted (packed stores).
__global__ __launch_bounds__(256) void gemm_mfma(const unsigned short* __restrict__ habf,
                                                 const unsigned short* __restrict__ wT,
                                                 const float* __restrict__ bias,
                                                 unsigned short* __restrict__ hnb,
                                                 unsigned char* __restrict__ xwb) {
    __shared__ __align__(16) unsigned short As[128][72];   // +8 pad
    __shared__ __align__(16) unsigned short Bs[128][72];
    int bid = blockIdx.x;
    int sm8 = bid & 7;
    int rest = bid >> 3;
    int n0 = rest % (RELS + 1);
    int g = rest / (RELS + 1);
    int stripe = g * 8 + sm8;
    if (stripe >= NSTRIPE) return;
    int row0 = stripe * 128;

    int tid = threadIdx.x;
    int wave = tid >> 6, lane = tid & 63;
    int wm = (wave & 1) * 64, wn = (wave >> 1) * 64;
    int quad = lane >> 4, l16 = lane & 15;

    f32x4 acc[4][4];
#pragma unroll
    for (int i = 0; i < 4; ++i)
#pragma unroll
        for (int j = 0; j < 4; ++j) acc[i][j] = (f32x4){0.f, 0.f, 0.f, 0.f};

    int srow = tid >> 1;          // 0..127
    int shalf = (tid & 1) * 32;   // 0 / 32 (bf16 elems)
    for (int k0 = 0; k0 < HID; k0 += 64) {
        int grow = row0 + srow;
        const uint4* ga = (const uint4*)(habf + (size_t)grow * HID + k0 + shalf);
        const uint4* gb = (const uint4*)(wT + (size_t)(n0 * 128 + srow) * HID + k0 + shalf);
        uint4 z = {0u, 0u, 0u, 0u};
#pragma unroll
        for (int c = 0; c < 4; ++c) {
            *(uint4*)&As[srow][shalf + c * 8] = (grow < NN) ? ga[c] : z;
            *(uint4*)&Bs[srow][shalf + c * 8] = gb[c];
        }
        __syncthreads();
#pragma unroll
        for (int kc = 0; kc < 2; ++kc) {
            int ko = kc * 32 + quad * 8;
            short8 a[4], b[4];
#pragma unroll
            for (int i = 0; i < 4; ++i) {
                a[i] = *(const short8*)&As[wm + i * 16 + l16][ko];
                b[i] = *(const short8*)&Bs[wn + i * 16 + l16][ko];
            }
#pragma unroll
            for (int i = 0; i < 4; ++i)
#pragma unroll
                for (int j = 0; j < 4; ++j)
                    acc[i][j] = __builtin_amdgcn_mfma_f32_16x16x32_bf16(a[i], b[j], acc[i][j], 0, 0, 0);
        }
        __syncthreads();
    }

    // epilogue (C/D: col=lane&15, row=quad*4+reg); packed stores at permuted positions
    int pbase = wn + l16 * 4;
    if (n0 == 0) {
#pragma unroll
        for (int i = 0; i < 4; ++i)
#pragma unroll
            for (int reg = 0; reg < 4; ++reg) {
                int grow = row0 + wm + i * 16 + quad * 4 + reg;
                if (grow >= NN) continue;
                unsigned lo = (unsigned)f2bf(acc[i][0][reg] + bias[wn + l16]) |
                              ((unsigned)f2bf(acc[i][1][reg] + bias[wn + 16 + l16]) << 16);
                unsigned hi = (unsigned)f2bf(acc[i][2][reg] + bias[wn + 32 + l16]) |
                              ((unsigned)f2bf(acc[i][3][reg] + bias[wn + 48 + l16]) << 16);
                uint2 pk = {lo, hi};
                *(uint2*)(hnb + (size_t)grow * HID + pbase) = pk;
            }
    } else {
        int cbase = (n0 - 1) * 128;
#pragma unroll
        for (int i = 0; i < 4; ++i)
#pragma unroll
            for (int reg = 0; reg < 4; ++reg) {
                int grow = row0 + wm + i * 16 + quad * 4 + reg;
                if (grow >= NN) continue;
                unsigned w = (unsigned)__builtin_amdgcn_cvt_pk_fp8_f32(acc[i][0][reg], acc[i][1][reg], 0, false);
                w = (unsigned)__builtin_amdgcn_cvt_pk_fp8_f32(acc[i][2][reg], acc[i][3][reg], (int)w, true);
                *(unsigned*)(xwb + (size_t)grow * (RELS * HID) + cbase + pbase) = w;
            }
    }
}

// ---------------- aggregate (atomic-free): 2 nodes per wave (32 lanes/node, uint=4 fp8/lane)
// position-wise: habf[dst] = relu(hnb[dst] + sum xwb[src][r]*s)
__global__ __launch_bounds__(256) void aggregate_kernel(const int* __restrict__ rowptr,
                                                        const int* __restrict__ epk,
                                                        const float* __restrict__ escale,
                                                        const unsigned char* __restrict__ xwb,
                                                        const unsigned short* __restrict__ hnb,
                                                        unsigned short* __restrict__ habf) {
    int lane = threadIdx.x & 63;
    int half = lane >> 5;          // 0/1: which node of this wave
    int hl = lane & 31;            // lane within node
    int node = (blockIdx.x << 3) + ((threadIdx.x >> 6) << 1) + half;
    if (node >= NN) return;
    int beg = rowptr[node], end = rowptr[node + 1];
    float a0 = 0.f, a1 = 0.f, a2 = 0.f, a3 = 0.f;
    for (int b0 = beg; b0 < end; b0 += 32) {
        int cnt = min(32, end - b0);
        int myp = 0; float mys = 0.f;
        if (hl < cnt) { myp = epk[b0 + hl]; mys = escale[b0 + hl]; }
        int sbase = half << 5;
        int j = 0;
        for (; j + 2 <= cnt; j += 2) {
            int p0 = __shfl(myp, sbase + j);
            int p1 = __shfl(myp, sbase + j + 1);
            float s0 = __shfl(mys, sbase + j);
            float s1 = __shfl(mys, sbase + j + 1);
            unsigned u0 = *(const unsigned*)(xwb + (size_t)(p0 & 0xFFFFF) * (RELS * HID) + (p0 >> 20) * HID + hl * 4);
            unsigned u1 = *(const unsigned*)(xwb + (size_t)(p1 & 0xFFFFF) * (RELS * HID) + (p1 >> 20) * HID + hl * 4);
            f32x2 l0 = fp8x2_2f<false>((int)u0), h0 = fp8x2_2f<true>((int)u0);
            f32x2 l1 = fp8x2_2f<false>((int)u1), h1 = fp8x2_2f<true>((int)u1);
            a0 += l0.x * s0 + l1.x * s1;
            a1 += l0.y * s0 + l1.y * s1;
            a2 += h0.x * s0 + h1.x * s1;
            a3 += h0.y * s0 + h1.y * s1;
        }
        for (; j < cnt; ++j) {
            int p = __shfl(myp, sbase + j);
            float s = __shfl(mys, sbase + j);
            unsigned u = *(const unsigned*)(xwb + (size_t)(p & 0xFFFFF) * (RELS * HID) + (p >> 20) * HID + hl * 4);
            f32x2 lo = fp8x2_2f<false>((int)u), hi = fp8x2_2f<true>((int)u);
            a0 += lo.x * s; a1 += lo.y * s; a2 += hi.x * s; a3 += hi.y * s;
        }
    }
    const ushort2* hp = (const ushort2*)(hnb + (size_t)node * HID + hl * 4);
    ushort2 c0 = hp[0], c1 = hp[1];
    ushort2 o0, o1;
    o0.x = f2bf(fmaxf(bf2f(c0.x) + a0, 0.f));
    o0.y = f2bf(fmaxf(bf2f(c0.y) + a1, 0.f));
    o1.x = f2bf(fmaxf(bf2f(c1.x) + a2, 0.f));
    o1.y = f2bf(fmaxf(bf2f(c1.y) + a3, 0.f));
    ushort2* op = (ushort2*)(habf + (size_t)node * HID + hl * 4);
    op[0] = o0;
    op[1] = o1;
}

// ---------------- global mean pool: sorted-batch register accumulation (position-wise)
__global__ __launch_bounds__(256) void pool_kernel(const unsigned short* __restrict__ habf,
                                                   const int* __restrict__ batch,
                                                   float* __restrict__ psum,
                                                   float* __restrict__ pcnt) {
    int tid = threadIdx.x;
    int f = tid & 127;
    int sub = tid >> 7;
    int base = blockIdx.x * PCHUNK;
    float acc = 0.f, cnt = 0.f;
    int gcur = -1;
    for (int it = 0; it < PCHUNK / 2; ++it) {
        int node = base + it * 2 + sub;
        if (node >= NN) break;
        int g = batch[node];
        if (g != gcur) {
            if (gcur >= 0) {
                atomicAdd(&psum[gcur * HID + f], acc);
                if (f == 0) atomicAdd(&pcnt[gcur], cnt);
            }
            gcur = g; acc = 0.f; cnt = 0.f;
        }
        acc += bf2f(habf[(size_t)node * HID + f]);
        cnt += 1.f;
    }
    if (gcur >= 0) {
        atomicAdd(&psum[gcur * HID + f], acc);
        if (f == 0) atomicAdd(&pcnt[gcur], cnt);
    }
}

// ---------------- head (unpermutes psum)
__global__ void head_kernel(const float* __restrict__ psum, const float* __restrict__ pcnt,
                            const float* __restrict__ g2, const float* __restrict__ b2,
                            const float* __restrict__ m2, const float* __restrict__ v2,
                            const float* __restrict__ fc1w, const float* __restrict__ fc1b,
                            const float* __restrict__ fc2w, const float* __restrict__ fc2b,
                            float* __restrict__ out) {
    __shared__ float v[HID];
    __shared__ float u[HID];
    __shared__ float lg[CLASSES];
    int j = threadIdx.x;
    int pj = permf(j);
    float acc = 0.f;
    for (int g = 0; g < GRAPHS; ++g) {
        float val = psum[g * HID + pj] / fmaxf(pcnt[g], 1.0f);
        val = (val - m2[j]) * rsqrtf(v2[j] + EPSV) * g2[j] + b2[j];
        acc += val;
    }
    v[j] = fmaxf(acc / (float)GRAPHS, 0.f);
    __syncthreads();
    float s = fc1b[j];
    for (int k = 0; k < HID; ++k) s += v[k] * fc1w[k * HID + j];
    u[j] = fmaxf(s, 0.f);
    __syncthreads();
    if (j < CLASSES) {
        float t = fc2b[j];
        for (int k = 0; k < HID; ++k) t += u[k] * fc2w[k * CLASSES + j];
        lg[j] = t;
    }
    __syncthreads();
    if (j < CLASSES) {
        float mx = lg[0];
        for (int c = 1; c < CLASSES; ++c) mx = fmaxf(mx, lg[c]);
        float se = 0.f;
        for (int c = 0; c < CLASSES; ++c) se += expf(lg[c] - mx);
        out[j] = lg[j] - mx - logf(se);
    }
}

extern "C" void kernel_launch(void* const* d_in, const int* in_sizes, int n_in,
                              void* d_out, int out_size, void* d_ws, size_t ws_size,
                              hipStream_t stream) {
    const float* x     = (const float*)d_in[0];
    const int*   ei    = (const int*)d_in[1];
    const int*   ea    = (const int*)d_in[2];
    const int*   batch = (const int*)d_in[3];
    const float* bn1g  = (const float*)d_in[4];
    const float* bn1b  = (const float*)d_in[5];
    const float* bn1m  = (const float*)d_in[6];
    const float* bn1v  = (const float*)d_in[7];
    const float* basis = (const float*)d_in[8];
    const float* comp  = (const float*)d_in[9];
    const float* root  = (const float*)d_in[10];
    const float* bias  = (const float*)d_in[11];
    const float* bn2g  = (const float*)d_in[12];
    const float* bn2b  = (const float*)d_in[13];
    const float* bn2m  = (const float*)d_in[14];
    const float* bn2v  = (const float*)d_in[15];
    const float* fc1w  = (const float*)d_in[16];
    const float* fc1b  = (const float*)d_in[17];
    const float* fc2w  = (const float*)d_in[18];
    const float* fc2b  = (const float*)d_in[19];

    float* ws = (float*)d_ws;
    size_t off = 0;
    unsigned short* wT = (unsigned short*)(ws + off); off += (size_t)LAYERS * NOUT * HID / 2;
    unsigned short* hnb  = (unsigned short*)(ws + off); off += (size_t)NN * HID / 2;
    unsigned short* habf = (unsigned short*)(ws + off); off += (size_t)NN * HID / 2;
    float* deg    = ws + off; off += (size_t)NN * RELS;
    float* psum   = ws + off; off += (size_t)GRAPHS * HID + GRAPHS;
    float* pcnt   = psum + GRAPHS * HID;
    float* escale = ws + off; off += (size_t)NE;
    int* degi     = (int*)(ws + off); off += (size_t)NN;
    int* rowptr   = (int*)(ws + off); off += (size_t)NN + 1;
    int* fillcnt  = (int*)(ws + off); off += (size_t)NN;
    int* bsum     = (int*)(ws + off); off += (size_t)SCAN_NBLK;
    int* epk      = (int*)(ws + off); off += (size_t)NE;
    off = (off + 3) & ~(size_t)3;
    unsigned char* xwb = (unsigned char*)(ws + off);
    off += (size_t)NN * RELS * HID / 4;                 // fp8: 51.2 MB
    if (ws_size < off * sizeof(float)) return;

    hipMemsetAsync(psum, 0, (GRAPHS * HID + GRAPHS) * sizeof(float), stream);
    hipMemsetAsync(deg, 0, (size_t)NN * RELS * sizeof(float), stream);
    hipMemsetAsync(fillcnt, 0, (size_t)NN * sizeof(int), stream);

    build_wcat<<<LAYERS * 64, 256, 0, stream>>>(basis, comp, root, wT);
    bn1_kernel<<<(NN * HID + 255) / 256, 256, 0, stream>>>(x, bn1g, bn1b, bn1m, bn1v, habf);

    deg_kernel<<<(NE + 255) / 256, 256, 0, stream>>>(ei, ea, deg);
    invdeg_kernel<<<(NN + 255) / 256, 256, 0, stream>>>(deg, degi);
    scan_partial<<<SCAN_NBLK, 256, 0, stream>>>(degi, rowptr, bsum);
    scan_bsum<<<1, 64, 0, stream>>>(bsum);
    scan_add<<<(NN + 255) / 256, 256, 0, stream>>>(rowptr, bsum);
    fill_kernel<<<(NE + 255) / 256, 256, 0, stream>>>(ei, ea, rowptr, deg, fillcnt, epk, escale);

    int gblocks = NSG * (RELS + 1) * 8;   // 49 * 9 * 8 = 3528 (9 tail blocks exit early)
    for (int l = 0; l < LAYERS; ++l) {
        gemm_mfma<<<gblocks, 256, 0, stream>>>(habf, wT + (size_t)l * NOUT * HID,
                                               bias + (size_t)l * HID, hnb, xwb);
        aggregate_kernel<<<(NN + 7) / 8, 256, 0, stream>>>(rowptr, epk, escale, xwb, hnb, habf);
    }

    pool_kernel<<<(NN + PCHUNK - 1) / PCHUNK, 256, 0, stream>>>(habf, batch, psum, pcnt);
    head_kernel<<<1, 128, 0, stream>>>(psum, pcnt, bn2g, bn2b, bn2m, bn2v,
                                       fc1w, fc1b, fc2w, fc2b, (float*)d_out);
}